// Round 1
// baseline (964.800 us; speedup 1.0000x reference)
//
#include <hip/hip_runtime.h>

// SelfAttentionHead: x:[16,2048,1024]f32, Wk/Wq/Wv:[1024,64]f32 -> out:[16,2048,64]f32
// Round 1: correct fp32 baseline.
//   Kernel 1 qkv_proj: fused q,k,v = x @ W{q,k,v}; LDS-tiled, float4 LDS reads.
//   Kernel 2 attn: flash-style causal attention, 64x64 tiles, online softmax.

constexpr int kE = 1024;
constexpr int kH = 64;
constexpr int kT = 2048;
constexpr int kB = 16;
constexpr int kM = kB * kT;   // 32768 rows

// ---------------------------------------------------------------- qkv_proj
// grid = kM/64 = 512 blocks, 256 threads. Block: 64 rows x 192 cols (q|k|v).
// Thread (tx,ty) = (tid&15, tid>>4): rows ty*4..+3, cols tx+16*jj, jj<12.
__global__ __launch_bounds__(256)
void qkv_proj(const float* __restrict__ x,
              const float* __restrict__ Wk,
              const float* __restrict__ Wq,
              const float* __restrict__ Wv,
              float* __restrict__ qo,
              float* __restrict__ ko,
              float* __restrict__ vo)
{
    // pad rows to 36 words: 144 B keeps every row float4-aligned, banks spread.
    __shared__ float xs[64][36];    // x tile   [row][k]
    __shared__ float wsT[192][36];  // W tiles  [outcol][k]  (0..63 Wq, 64..127 Wk, 128..191 Wv)

    const int tid = threadIdx.x;
    const int tx = tid & 15;
    const int ty = tid >> 4;
    const int row0 = blockIdx.x * 64;

    float acc[4][12];
    #pragma unroll
    for (int r = 0; r < 4; ++r)
        #pragma unroll
        for (int j = 0; j < 12; ++j) acc[r][j] = 0.f;

    for (int k0 = 0; k0 < kE; k0 += 32) {
        // stage x tile: 64x32 = 512 float4 loads (coalesced)
        #pragma unroll
        for (int i = 0; i < 2; ++i) {
            int idx = tid + i * 256;            // 0..511
            int r = idx >> 3, c4 = idx & 7;
            float4 val = *(const float4*)&x[(size_t)(row0 + r) * kE + k0 + c4 * 4];
            *(float4*)&xs[r][c4 * 4] = val;
        }
        // stage W tiles transposed: 3 x (32x64), float4 global reads, scalar LDS scatter
        #pragma unroll
        for (int i = 0; i < 2; ++i) {
            int idx = tid + i * 256;            // 0..511
            int kk = idx >> 4, c4 = idx & 15;
            const size_t goff = (size_t)(k0 + kk) * kH + c4 * 4;
            float4 wq = *(const float4*)&Wq[goff];
            float4 wk = *(const float4*)&Wk[goff];
            float4 wv = *(const float4*)&Wv[goff];
            const int c = c4 * 4;
            wsT[c + 0][kk] = wq.x;  wsT[c + 1][kk] = wq.y;
            wsT[c + 2][kk] = wq.z;  wsT[c + 3][kk] = wq.w;
            wsT[64 + c + 0][kk] = wk.x;  wsT[64 + c + 1][kk] = wk.y;
            wsT[64 + c + 2][kk] = wk.z;  wsT[64 + c + 3][kk] = wk.w;
            wsT[128 + c + 0][kk] = wv.x; wsT[128 + c + 1][kk] = wv.y;
            wsT[128 + c + 2][kk] = wv.z; wsT[128 + c + 3][kk] = wv.w;
        }
        __syncthreads();

        #pragma unroll
        for (int k4 = 0; k4 < 8; ++k4) {        // 4 k-steps per iter, all b128 reads
            float4 a[4];
            #pragma unroll
            for (int rr = 0; rr < 4; ++rr)
                a[rr] = ((const float4*)&xs[ty * 4 + rr][0])[k4];
            #pragma unroll
            for (int jj = 0; jj < 12; ++jj) {
                float4 b = ((const float4*)&wsT[tx + 16 * jj][0])[k4];
                #pragma unroll
                for (int rr = 0; rr < 4; ++rr) {
                    acc[rr][jj] += a[rr].x * b.x;
                    acc[rr][jj] += a[rr].y * b.y;
                    acc[rr][jj] += a[rr].z * b.z;
                    acc[rr][jj] += a[rr].w * b.w;
                }
            }
        }
        __syncthreads();
    }

    #pragma unroll
    for (int rr = 0; rr < 4; ++rr) {
        const size_t row = row0 + ty * 4 + rr;
        #pragma unroll
        for (int jj = 0; jj < 12; ++jj) {
            const int c = tx + 16 * jj;
            const float val = acc[rr][jj];
            if (c < 64)       qo[row * kH + c] = val;
            else if (c < 128) ko[row * kH + (c - 64)] = val;
            else              vo[row * kH + (c - 128)] = val;
        }
    }
}

// ---------------------------------------------------------------- attn
// grid = 16 batches * 32 q-tiles = 512 blocks, 256 threads.
// Flash-style: per 64-row q-tile, sweep causal k/v 64-row tiles with online softmax.
// Thread (tx,ty): S rows ty*4..+3 (16 contiguous lanes share a row group),
// S cols / O cols tx*4..+3.
__global__ __launch_bounds__(256)
void attn(const float* __restrict__ qm,
          const float* __restrict__ km,
          const float* __restrict__ vm,
          float* __restrict__ out)
{
    __shared__ float Qs[64][68];   // 68-word rows: float4-aligned, conflict-light
    __shared__ float Ks[64][68];
    __shared__ float Vs[64][68];
    __shared__ float Ps[64][68];

    const int tid = threadIdx.x;
    const int tx = tid & 15;
    const int ty = tid >> 4;
    const int batch = blockIdx.x >> 5;
    const int qi = blockIdx.x & 31;
    const int q0 = qi * 64;
    const float* qb = qm + (size_t)batch * kT * kH;
    const float* kb = km + (size_t)batch * kT * kH;
    const float* vb = vm + (size_t)batch * kT * kH;

    // load Q tile, pre-scaled by H^-0.5 = 0.125
    #pragma unroll
    for (int i = 0; i < 4; ++i) {
        int idx = tid + i * 256;               // 1024 float4s
        int r = idx >> 4, c4 = idx & 15;
        float4 val = *(const float4*)&qb[(size_t)(q0 + r) * kH + c4 * 4];
        val.x *= 0.125f; val.y *= 0.125f; val.z *= 0.125f; val.w *= 0.125f;
        *(float4*)&Qs[r][c4 * 4] = val;
    }

    float O[4][4];
    float m_i[4], l_i[4];
    #pragma unroll
    for (int rr = 0; rr < 4; ++rr) {
        m_i[rr] = -1e30f;
        l_i[rr] = 0.f;
        #pragma unroll
        for (int cc = 0; cc < 4; ++cc) O[rr][cc] = 0.f;
    }

    for (int kt = 0; kt <= qi; ++kt) {
        const int s0 = kt * 64;
        #pragma unroll
        for (int i = 0; i < 4; ++i) {
            int idx = tid + i * 256;
            int r = idx >> 4, c4 = idx & 15;
            const size_t goff = (size_t)(s0 + r) * kH + c4 * 4;
            *(float4*)&Ks[r][c4 * 4] = *(const float4*)&kb[goff];
            *(float4*)&Vs[r][c4 * 4] = *(const float4*)&vb[goff];
        }
        __syncthreads();   // also covers initial Qs staging on first iter

        // S = Q K^T : 4x4 fragment, K-dim vectorized float4
        float s[4][4];
        #pragma unroll
        for (int rr = 0; rr < 4; ++rr)
            #pragma unroll
            for (int ss = 0; ss < 4; ++ss) s[rr][ss] = 0.f;

        #pragma unroll
        for (int k4 = 0; k4 < 16; ++k4) {
            float4 a[4], b[4];
            #pragma unroll
            for (int rr = 0; rr < 4; ++rr)
                a[rr] = ((const float4*)&Qs[ty * 4 + rr][0])[k4];
            #pragma unroll
            for (int ss = 0; ss < 4; ++ss)
                b[ss] = ((const float4*)&Ks[tx * 4 + ss][0])[k4];
            #pragma unroll
            for (int rr = 0; rr < 4; ++rr)
                #pragma unroll
                for (int ss = 0; ss < 4; ++ss)
                    s[rr][ss] += a[rr].x * b[ss].x + a[rr].y * b[ss].y
                               + a[rr].z * b[ss].z + a[rr].w * b[ss].w;
        }

        if (kt == qi) {   // causal mask, diagonal tile only
            #pragma unroll
            for (int rr = 0; rr < 4; ++rr)
                #pragma unroll
                for (int ss = 0; ss < 4; ++ss)
                    if (s0 + tx * 4 + ss > q0 + ty * 4 + rr) s[rr][ss] = -1e30f;
        }

        // online softmax (per q-row; 16 lanes share a row)
        #pragma unroll
        for (int rr = 0; rr < 4; ++rr) {
            float rmax = fmaxf(fmaxf(s[rr][0], s[rr][1]), fmaxf(s[rr][2], s[rr][3]));
            #pragma unroll
            for (int off = 8; off >= 1; off >>= 1)
                rmax = fmaxf(rmax, __shfl_xor(rmax, off, 16));
            const float mnew = fmaxf(m_i[rr], rmax);
            const float alpha = __expf(m_i[rr] - mnew);
            float rsum = 0.f;
            #pragma unroll
            for (int ss = 0; ss < 4; ++ss) {
                s[rr][ss] = __expf(s[rr][ss] - mnew);
                rsum += s[rr][ss];
            }
            #pragma unroll
            for (int off = 8; off >= 1; off >>= 1)
                rsum += __shfl_xor(rsum, off, 16);
            l_i[rr] = l_i[rr] * alpha + rsum;
            m_i[rr] = mnew;
            #pragma unroll
            for (int cc = 0; cc < 4; ++cc) O[rr][cc] *= alpha;
            *(float4*)&Ps[ty * 4 + rr][tx * 4] =
                make_float4(s[rr][0], s[rr][1], s[rr][2], s[rr][3]);
        }
        __syncthreads();   // P visible before PV

        // O += P V  (s-dim vectorized float4)
        #pragma unroll
        for (int s4 = 0; s4 < 16; ++s4) {
            float4 a[4], bv[4];
            #pragma unroll
            for (int rr = 0; rr < 4; ++rr)
                a[rr] = ((const float4*)&Ps[ty * 4 + rr][0])[s4];
            #pragma unroll
            for (int i = 0; i < 4; ++i)
                bv[i] = *(const float4*)&Vs[s4 * 4 + i][tx * 4];
            #pragma unroll
            for (int rr = 0; rr < 4; ++rr) {
                O[rr][0] += a[rr].x * bv[0].x + a[rr].y * bv[1].x
                          + a[rr].z * bv[2].x + a[rr].w * bv[3].x;
                O[rr][1] += a[rr].x * bv[0].y + a[rr].y * bv[1].y
                          + a[rr].z * bv[2].y + a[rr].w * bv[3].y;
                O[rr][2] += a[rr].x * bv[0].z + a[rr].y * bv[1].z
                          + a[rr].z * bv[2].z + a[rr].w * bv[3].z;
                O[rr][3] += a[rr].x * bv[0].w + a[rr].y * bv[1].w
                          + a[rr].z * bv[2].w + a[rr].w * bv[3].w;
            }
        }
        __syncthreads();   // protect Ks/Vs/Ps before next stage
    }

    #pragma unroll
    for (int rr = 0; rr < 4; ++rr) {
        const float inv = 1.0f / l_i[rr];
        const size_t row = (size_t)batch * kT + q0 + ty * 4 + rr;
        #pragma unroll
        for (int cc = 0; cc < 4; ++cc)
            out[row * kH + tx * 4 + cc] = O[rr][cc] * inv;
    }
}

extern "C" void kernel_launch(void* const* d_in, const int* in_sizes, int n_in,
                              void* d_out, int out_size, void* d_ws, size_t ws_size,
                              hipStream_t stream)
{
    (void)in_sizes; (void)n_in; (void)out_size; (void)ws_size;
    const float* x  = (const float*)d_in[0];
    const float* Wk = (const float*)d_in[1];
    const float* Wq = (const float*)d_in[2];
    const float* Wv = (const float*)d_in[3];
    // workspace: q,k,v intermediates, 3 * 32768*64 * 4 B = 24 MiB
    float* q = (float*)d_ws;
    float* k = q + (size_t)kM * kH;
    float* v = k + (size_t)kM * kH;

    qkv_proj<<<kM / 64, 256, 0, stream>>>(x, Wk, Wq, Wv, q, k, v);
    attn<<<kB * (kT / 64), 256, 0, stream>>>(q, k, v, (float*)d_out);
}

// Round 2
// 271.557 us; speedup vs baseline: 3.5528x; 3.5528x over previous
//
#include <hip/hip_runtime.h>

// SelfAttentionHead R2: bf16 MFMA pipeline.
//  prep_w : Wq|Wk|Wv f32 [1024][64] -> WbT bf16 [192][1024] (n-major, k contiguous)
//  qkv    : x f32 -> q,k,v bf16 [32768][64] via 16x16x32 bf16 MFMA (q pre-scaled)
//  attn   : flash causal attention, MFMA QK^T + PV, online softmax (exp2 domain)
// MFMA 16x16x32 bf16 layouts (verified m89/m91/m120):
//  A[m=lane&15][k=(lane>>4)*8+j]  B[k=(lane>>4)*8+j][n=lane&15]
//  C/D: col=lane&15, row=(lane>>4)*4+reg
// LDS pitch 72 bf16 (144 B): 16B-aligned rows, frag reads are 2-way bank (free).

typedef __bf16 bf16x8 __attribute__((ext_vector_type(8)));
typedef float f32x4 __attribute__((ext_vector_type(4)));

constexpr int kE = 1024;
constexpr int kH = 64;
constexpr int kT = 2048;
constexpr int kB = 16;
constexpr int kM = kB * kT;                       // 32768
constexpr float kQScale = 0.125f * 1.44269504088896340736f;  // H^-0.5 * log2(e)

#define MFMA16(a, b, c) __builtin_amdgcn_mfma_f32_16x16x32_bf16((a), (b), (c), 0, 0, 0)

// ---------------------------------------------------------------- prep_w
// 48 blocks (mat 0..2 x 16 k-tiles), 256 threads. Transpose-convert one 64x64 tile.
__global__ __launch_bounds__(256)
void prep_w(const float* __restrict__ Wq, const float* __restrict__ Wk,
            const float* __restrict__ Wv, __bf16* __restrict__ WbT)
{
    __shared__ float tl[64][65];   // [col][k] transposed f32 tile
    const int mat = blockIdx.x >> 4;
    const int k0 = (blockIdx.x & 15) * 64;
    const float* src = (mat == 0) ? Wq : (mat == 1) ? Wk : Wv;

    const int t = threadIdx.x;
    const int kr = t >> 2;
    const int cg = (t & 3) * 16;
    #pragma unroll
    for (int i = 0; i < 4; ++i) {
        float4 v = *(const float4*)&src[(size_t)(k0 + kr) * kH + cg + 4 * i];
        tl[cg + 4 * i + 0][kr] = v.x;
        tl[cg + 4 * i + 1][kr] = v.y;
        tl[cg + 4 * i + 2][kr] = v.z;
        tl[cg + 4 * i + 3][kr] = v.w;
    }
    __syncthreads();
    const int nl = t >> 2;
    const int kg = (t & 3) * 16;
    bf16x8 o0, o1;
    #pragma unroll
    for (int j = 0; j < 8; ++j) {
        o0[j] = (__bf16)tl[nl][kg + j];
        o1[j] = (__bf16)tl[nl][kg + 8 + j];
    }
    *(bf16x8*)&WbT[(size_t)(mat * 64 + nl) * kE + k0 + kg] = o0;
    *(bf16x8*)&WbT[(size_t)(mat * 64 + nl) * kE + k0 + kg + 8] = o1;
}

// ---------------------------------------------------------------- qkv
// 512 blocks, 256 threads (4 waves). Block: 64 rows x 192 cols.
// Wave w: n-tiles 3w..3w+2 (cols 48w..48w+47), all 4 m-tiles.
__global__ __launch_bounds__(256)
void qkv(const float* __restrict__ x, const __bf16* __restrict__ WbT,
         __bf16* __restrict__ qo, __bf16* __restrict__ ko, __bf16* __restrict__ vo)
{
    __shared__ __align__(16) __bf16 As[64][72];
    __shared__ __align__(16) __bf16 Bs[192][72];

    const int t = threadIdx.x;
    const int lane = t & 63;
    const int w = t >> 6;
    const int l15 = lane & 15;
    const int q = lane >> 4;
    const int row0 = blockIdx.x * 64;

    f32x4 acc[4][3];
    #pragma unroll
    for (int mt = 0; mt < 4; ++mt)
        #pragma unroll
        for (int nt = 0; nt < 3; ++nt) acc[mt][nt] = (f32x4){0.f, 0.f, 0.f, 0.f};

    const int sm = t >> 2;          // staging row 0..63
    const int sc = (t & 3) * 16;    // staging col group

    for (int k0 = 0; k0 < kE; k0 += 64) {
        // stage A: 64x64 f32 -> bf16. thread: row sm, cols sc..sc+15
        {
            float4 v0 = *(const float4*)&x[(size_t)(row0 + sm) * kE + k0 + sc];
            float4 v1 = *(const float4*)&x[(size_t)(row0 + sm) * kE + k0 + sc + 4];
            float4 v2 = *(const float4*)&x[(size_t)(row0 + sm) * kE + k0 + sc + 8];
            float4 v3 = *(const float4*)&x[(size_t)(row0 + sm) * kE + k0 + sc + 12];
            bf16x8 b0, b1;
            b0[0] = (__bf16)v0.x; b0[1] = (__bf16)v0.y; b0[2] = (__bf16)v0.z; b0[3] = (__bf16)v0.w;
            b0[4] = (__bf16)v1.x; b0[5] = (__bf16)v1.y; b0[6] = (__bf16)v1.z; b0[7] = (__bf16)v1.w;
            b1[0] = (__bf16)v2.x; b1[1] = (__bf16)v2.y; b1[2] = (__bf16)v2.z; b1[3] = (__bf16)v2.w;
            b1[4] = (__bf16)v3.x; b1[5] = (__bf16)v3.y; b1[6] = (__bf16)v3.z; b1[7] = (__bf16)v3.w;
            *(bf16x8*)&As[sm][sc] = b0;
            *(bf16x8*)&As[sm][sc + 8] = b1;
        }
        // stage B: 192x64 bf16, 1536 16B chunks, 6 per thread
        #pragma unroll
        for (int j = 0; j < 6; ++j) {
            int id = t + 256 * j;
            int n = id >> 3;
            int kc = (id & 7) * 8;
            *(bf16x8*)&Bs[n][kc] = *(const bf16x8*)&WbT[(size_t)n * kE + k0 + kc];
        }
        __syncthreads();

        #pragma unroll
        for (int ks = 0; ks < 2; ++ks) {
            bf16x8 a4[4];
            #pragma unroll
            for (int mt = 0; mt < 4; ++mt)
                a4[mt] = *(const bf16x8*)&As[mt * 16 + l15][ks * 32 + q * 8];
            #pragma unroll
            for (int nt = 0; nt < 3; ++nt) {
                bf16x8 b = *(const bf16x8*)&Bs[w * 48 + nt * 16 + l15][ks * 32 + q * 8];
                #pragma unroll
                for (int mt = 0; mt < 4; ++mt)
                    acc[mt][nt] = MFMA16(a4[mt], b, acc[mt][nt]);
            }
        }
        __syncthreads();
    }

    // epilogue: C-layout scatter, bf16 stores. q gets exp2-domain scale.
    #pragma unroll
    for (int nt = 0; nt < 3; ++nt) {
        const int col0 = w * 48 + nt * 16;
        const int mat = col0 >> 6;
        const int c = (col0 & 63) + l15;
        __bf16* dst = (mat == 0) ? qo : (mat == 1) ? ko : vo;
        const float sc_ = (mat == 0) ? kQScale : 1.0f;
        #pragma unroll
        for (int mt = 0; mt < 4; ++mt)
            #pragma unroll
            for (int r = 0; r < 4; ++r) {
                const size_t row = row0 + mt * 16 + q * 4 + r;
                dst[row * kH + c] = (__bf16)(acc[mt][nt][r] * sc_);
            }
    }
}

// ---------------------------------------------------------------- attn
// 512 blocks (qi DESCENDING for load balance), 256 threads (4 waves).
// Block: 64-row q-tile. Wave w: rows w*16..w*16+15 of the tile.
__global__ __launch_bounds__(256)
void attn(const __bf16* __restrict__ qm, const __bf16* __restrict__ km,
          const __bf16* __restrict__ vm, float* __restrict__ out)
{
    __shared__ __align__(16) __bf16 Qs[64][72];
    __shared__ __align__(16) __bf16 Ks[64][72];
    __shared__ __align__(16) __bf16 Vt[64][72];     // V transposed: [h][s]
    __shared__ __align__(16) __bf16 Ps[4][16][72];  // per-wave P strip

    const int t = threadIdx.x;
    const int lane = t & 63;
    const int w = t >> 6;
    const int l15 = lane & 15;
    const int q = lane >> 4;

    const int batch = blockIdx.x & 15;
    const int qi = 31 - (blockIdx.x >> 4);          // long blocks first
    const int q0 = qi * 64;

    const __bf16* qb = qm + (size_t)batch * kT * kH;
    const __bf16* kb = km + (size_t)batch * kT * kH;
    const __bf16* vb = vm + (size_t)batch * kT * kH;

    const int sm = t >> 2;
    const int sc = (t & 3) * 16;

    // stage Q tile (wave-local rows: sm in [16w,16w+16))
    *(bf16x8*)&Qs[sm][sc]     = *(const bf16x8*)&qb[(size_t)(q0 + sm) * kH + sc];
    *(bf16x8*)&Qs[sm][sc + 8] = *(const bf16x8*)&qb[(size_t)(q0 + sm) * kH + sc + 8];
    bf16x8 aq[2];
    #pragma unroll
    for (int ks = 0; ks < 2; ++ks)
        aq[ks] = *(const bf16x8*)&Qs[w * 16 + l15][ks * 32 + q * 8];

    f32x4 O[4];
    float m4[4], l4[4];
    #pragma unroll
    for (int i = 0; i < 4; ++i) {
        O[i] = (f32x4){0.f, 0.f, 0.f, 0.f};
        m4[i] = -1e30f; l4[i] = 0.f;
    }

    for (int kt = 0; kt <= qi; ++kt) {
        const int s0 = kt * 64;
        // stage K row-major, V transposed
        *(bf16x8*)&Ks[sm][sc]     = *(const bf16x8*)&kb[(size_t)(s0 + sm) * kH + sc];
        *(bf16x8*)&Ks[sm][sc + 8] = *(const bf16x8*)&kb[(size_t)(s0 + sm) * kH + sc + 8];
        {
            bf16x8 v0 = *(const bf16x8*)&vb[(size_t)(s0 + sm) * kH + sc];
            bf16x8 v1 = *(const bf16x8*)&vb[(size_t)(s0 + sm) * kH + sc + 8];
            #pragma unroll
            for (int j = 0; j < 8; ++j) {
                Vt[sc + j][sm] = v0[j];
                Vt[sc + 8 + j][sm] = v1[j];
            }
        }
        __syncthreads();

        // S = Q K^T
        f32x4 sacc[4];
        #pragma unroll
        for (int nt = 0; nt < 4; ++nt) sacc[nt] = (f32x4){0.f, 0.f, 0.f, 0.f};
        #pragma unroll
        for (int ks = 0; ks < 2; ++ks)
            #pragma unroll
            for (int nt = 0; nt < 4; ++nt) {
                bf16x8 b = *(const bf16x8*)&Ks[nt * 16 + l15][ks * 32 + q * 8];
                sacc[nt] = MFMA16(aq[ks], b, sacc[nt]);
            }

        if (kt == qi) {   // causal mask on diagonal tile
            #pragma unroll
            for (int nt = 0; nt < 4; ++nt) {
                const int scol = s0 + nt * 16 + l15;
                #pragma unroll
                for (int r = 0; r < 4; ++r)
                    if (scol > q0 + w * 16 + q * 4 + r) sacc[nt][r] = -1e30f;
            }
        }

        // online softmax per row (exp2 domain; q pre-scaled by 0.125*log2e)
        #pragma unroll
        for (int r = 0; r < 4; ++r) {
            float mx = fmaxf(fmaxf(sacc[0][r], sacc[1][r]), fmaxf(sacc[2][r], sacc[3][r]));
            #pragma unroll
            for (int off = 1; off < 16; off <<= 1)
                mx = fmaxf(mx, __shfl_xor(mx, off, 16));
            const float mnew = fmaxf(m4[r], mx);
            const float alpha = __builtin_amdgcn_exp2f(m4[r] - mnew);
            float rs = 0.f;
            #pragma unroll
            for (int nt = 0; nt < 4; ++nt) {
                const float p = __builtin_amdgcn_exp2f(sacc[nt][r] - mnew);
                sacc[nt][r] = p;
                rs += p;
            }
            #pragma unroll
            for (int off = 1; off < 16; off <<= 1)
                rs += __shfl_xor(rs, off, 16);
            l4[r] = l4[r] * alpha + rs;
            m4[r] = mnew;
            #pragma unroll
            for (int ht = 0; ht < 4; ++ht) O[ht][r] *= alpha;
            #pragma unroll
            for (int nt = 0; nt < 4; ++nt)
                Ps[w][q * 4 + r][nt * 16 + l15] = (__bf16)sacc[nt][r];
        }

        // O += P V (P wave-local in LDS; compiler inserts lgkmcnt)
        #pragma unroll
        for (int ss = 0; ss < 2; ++ss) {
            bf16x8 ap = *(const bf16x8*)&Ps[w][l15][ss * 32 + q * 8];
            #pragma unroll
            for (int ht = 0; ht < 4; ++ht) {
                bf16x8 bv = *(const bf16x8*)&Vt[ht * 16 + l15][ss * 32 + q * 8];
                O[ht] = MFMA16(ap, bv, O[ht]);
            }
        }
        __syncthreads();   // protect Ks/Vt before next stage
    }

    #pragma unroll
    for (int r = 0; r < 4; ++r) {
        const float inv = 1.0f / l4[r];
        const size_t row = (size_t)batch * kT + q0 + w * 16 + q * 4 + r;
        #pragma unroll
        for (int ht = 0; ht < 4; ++ht)
            out[row * kH + ht * 16 + l15] = O[ht][r] * inv;
    }
}

extern "C" void kernel_launch(void* const* d_in, const int* in_sizes, int n_in,
                              void* d_out, int out_size, void* d_ws, size_t ws_size,
                              hipStream_t stream)
{
    (void)in_sizes; (void)n_in; (void)out_size; (void)ws_size;
    const float* x  = (const float*)d_in[0];
    const float* Wk = (const float*)d_in[1];
    const float* Wq = (const float*)d_in[2];
    const float* Wv = (const float*)d_in[3];

    // ws layout: WbT bf16 [192][1024] (384 KiB), then q,k,v bf16 [32768][64] (4 MiB each)
    __bf16* WbT = (__bf16*)d_ws;
    __bf16* qb = WbT + (size_t)192 * kE;
    __bf16* kbuf = qb + (size_t)kM * kH;
    __bf16* vbuf = kbuf + (size_t)kM * kH;

    prep_w<<<48, 256, 0, stream>>>(Wq, Wk, Wv, WbT);
    qkv<<<kM / 64, 256, 0, stream>>>(x, WbT, qb, kbuf, vbuf);
    attn<<<kB * (kT / 64), 256, 0, stream>>>(qb, kbuf, vbuf, (float*)d_out);
}